// Round 3
// baseline (1197.807 us; speedup 1.0000x reference)
//
#include <hip/hip_runtime.h>
#include <hip/hip_bf16.h>
#include <stdint.h>

// ============================================================================
// MinGRU (2 layers), B=8 S=4096 D=H=1024.
//   1. x (f32) -> bf16
//   2. GEMM0: gh = x_bf16 @ W0^T + b0  -> bf16 gh   (M=32768,N=2048,K=1024)
//   3. scan0: fused sigmoid/g + chunked linear scan -> h1 (bf16)
//   4. GEMM1: gh = h1 @ W1^T + b1 -> bf16 gh
//   5. scan1: -> out (f32)
// R3: GEMM streams B (weights, L2-resident 4MB) directly global->frag regs,
//     LDS holds only A (16KB). gh stored bf16; scans vector-loaded 4ch/thread.
// ============================================================================

typedef __attribute__((ext_vector_type(8))) short bf16x8;   // 8 bf16 = 4 VGPRs
typedef __attribute__((ext_vector_type(4))) float f32x4;

__device__ __forceinline__ unsigned short f2bf(float f) {
    union { float f; unsigned int u; } x; x.f = f;
    unsigned int r = x.u + 0x7fffu + ((x.u >> 16) & 1u);   // RNE
    return (unsigned short)(r >> 16);
}
__device__ __forceinline__ float bf2f(unsigned short u) {
    union { unsigned int i; float f; } x; x.i = ((unsigned int)u) << 16;
    return x.f;
}
__device__ __forceinline__ float sigmoidf_(float x) {
    return 1.0f / (1.0f + __expf(-x));
}

// async 16B/lane global->LDS. lds base wave-uniform; HW dest = lds + lane*16.
__device__ __forceinline__ void async_cp16(const void* g, void* lds) {
    __builtin_amdgcn_global_load_lds(
        (const __attribute__((address_space(1))) unsigned int*)g,
        (__attribute__((address_space(3))) unsigned int*)lds, 16, 0, 0);
}

// ---------------------------------------------------------------------------
__global__ void f32_to_bf16_k(const float* __restrict__ in,
                              unsigned short* __restrict__ out, int n8) {
    int i = blockIdx.x * blockDim.x + threadIdx.x;
    if (i >= n8) return;
    const float4* p = reinterpret_cast<const float4*>(in);
    float4 a = p[2 * i], b = p[2 * i + 1];
    float f[8] = {a.x, a.y, a.z, a.w, b.x, b.y, b.z, b.w};
    union { unsigned short s[8]; uint4 v; } u;
#pragma unroll
    for (int j = 0; j < 8; ++j) u.s[j] = f2bf(f[j]);
    *reinterpret_cast<uint4*>(out + (size_t)i * 8) = u.v;
}

// ---------------------------------------------------------------------------
// GEMM: C[m,n] = sum_k A[m,k]*Wt[n,k] + bias[n], C stored bf16.
// 128x128 tile, BK=64, 4 waves (2x2). A staged in LDS (fragment order, 16KB,
// global_load_lds). B fragments loaded straight from global: lanes
// {r,r+16,r+32,r+48} cover one 64B line of row n0+tile*16+r.
// ---------------------------------------------------------------------------
__global__ __launch_bounds__(256) void gemm_bt(
    const short* __restrict__ A, const short* __restrict__ Wt,
    const float* __restrict__ bias, unsigned short* __restrict__ C,
    int M, int N, int K)
{
    __shared__ __align__(16) short lds_a[8192];   // 16KB: A tile 128x64 bf16

    const int tid  = threadIdx.x;
    const int lane = tid & 63;
    const int wave = tid >> 6;
    const int wm   = wave >> 1;            // 0..1
    const int wn   = wave & 1;             // 0..1
    const int m0   = blockIdx.x * 128;
    const int n0   = blockIdx.y * 128;

    f32x4 acc[4][4] = {};

    // A staging: chunk c = wave*64 + lane + i*256, i=0..3 (1024 chunks x 16B)
    const short* ga[4]; short* la[4];
#pragma unroll
    for (int i = 0; i < 4; ++i) {
        int c   = tid + i * 256;
        int blk = c >> 6;                       // 0..15: tma=blk>>1, kc=blk&1
        int L   = c & 63;
        int row = (blk >> 1) * 16 + (L & 15);
        int col = (blk & 1) * 32 + ((L >> 4) * 8);
        ga[i] = A + (size_t)(m0 + row) * K + col;
        la[i] = lds_a + (wave * 64 + i * 256) * 8;   // lane*16B implicit
    }

    // B fragment base pointers (per n-tile); frag = 16B at +k0+kc*32
    const short* gwb[4];
#pragma unroll
    for (int t = 0; t < 4; ++t) {
        int n = n0 + (wn * 4 + t) * 16 + (lane & 15);
        gwb[t] = Wt + (size_t)n * K + ((lane >> 4) * 8);
    }

    for (int k0 = 0; k0 < K; k0 += 64) {
#pragma unroll
        for (int i = 0; i < 4; ++i) async_cp16(ga[i] + k0, la[i]);
        // B fragments for both kc, direct from global (L2-hot weights)
        bf16x8 bf[2][4];
#pragma unroll
        for (int kc = 0; kc < 2; ++kc)
#pragma unroll
            for (int t = 0; t < 4; ++t)
                bf[kc][t] = *reinterpret_cast<const bf16x8*>(gwb[t] + k0 + kc * 32);
        __syncthreads();   // drains vmcnt: A tile in LDS (and bf in regs)
#pragma unroll
        for (int kc = 0; kc < 2; ++kc) {
            bf16x8 af[4];
#pragma unroll
            for (int t = 0; t < 4; ++t) {
                int tma = wm * 4 + t;
                af[t] = *reinterpret_cast<const bf16x8*>(lds_a + ((tma * 2 + kc) * 64 + lane) * 8);
            }
#pragma unroll
            for (int tm = 0; tm < 4; ++tm)
#pragma unroll
                for (int tn = 0; tn < 4; ++tn)
                    acc[tm][tn] = __builtin_amdgcn_mfma_f32_16x16x32_bf16(
                        af[tm], bf[kc][tn], acc[tm][tn], 0, 0, 0);
        }
        __syncthreads();   // protect lds_a overwrite
    }

    // epilogue: C/D layout col=lane&15, row=quad*4+reg; store bf16
    const int quad = lane >> 4;
    const int lcol = lane & 15;
#pragma unroll
    for (int tm = 0; tm < 4; ++tm) {
        int mrow = m0 + wm * 64 + tm * 16 + quad * 4;
#pragma unroll
        for (int tn = 0; tn < 4; ++tn) {
            int ecol = n0 + wn * 64 + tn * 16 + lcol;
            float bv = bias[ecol];
#pragma unroll
            for (int r = 0; r < 4; ++r)
                C[(size_t)(mrow + r) * N + ecol] = f2bf(acc[tm][tn][r] + bv);
        }
    }
}

// ---------------------------------------------------------------------------
// Scans over bf16 gh:(B*S,2048); gate=[0,1024), hidden=[1024,2048).
// 64 chunks of 64 steps; 4 channels/thread (8B loads). ch = b*1024+h.
// ---------------------------------------------------------------------------
__global__ void scan_partial(const unsigned short* __restrict__ gh,
                             float* __restrict__ P, float* __restrict__ V) {
    const int h4 = threadIdx.x;                 // 0..255 -> channels h4*4..+3
    const int j = blockIdx.y, b = blockIdx.z;
    const size_t base = ((size_t)b * 4096 + (size_t)j * 64) * 2048 + h4 * 4;
    float p[4] = {1, 1, 1, 1}, hl[4] = {0, 0, 0, 0};
#pragma unroll 8
    for (int t = 0; t < 64; ++t) {
        ushort4 g  = *reinterpret_cast<const ushort4*>(gh + base + (size_t)t * 2048);
        ushort4 hd = *reinterpret_cast<const ushort4*>(gh + base + (size_t)t * 2048 + 1024);
        const unsigned short ga[4] = {g.x, g.y, g.z, g.w};
        const unsigned short ha[4] = {hd.x, hd.y, hd.z, hd.w};
#pragma unroll
        for (int c = 0; c < 4; ++c) {
            float gf = bf2f(ga[c]), hf = bf2f(ha[c]);
            float z  = sigmoidf_(gf);
            float cc = 1.0f - z;
            float gv = (hf >= 0.0f) ? (hf + 0.5f) : sigmoidf_(hf);
            p[c]  = p[c] * cc;
            hl[c] = cc * hl[c] + z * gv;
        }
    }
    const int ch = b * 1024 + h4 * 4;
    *reinterpret_cast<float4*>(P + (size_t)j * 8192 + ch) = make_float4(p[0], p[1], p[2], p[3]);
    *reinterpret_cast<float4*>(V + (size_t)j * 8192 + ch) = make_float4(hl[0], hl[1], hl[2], hl[3]);
}

__global__ void scan_combine(const float* __restrict__ P,
                             const float* __restrict__ V,
                             float* __restrict__ hstart) {
    const int c4 = blockIdx.x * blockDim.x + threadIdx.x;  // 0..2047
    float4 h = make_float4(0.5f, 0.5f, 0.5f, 0.5f);        // h0 = g(0) = 0.5
#pragma unroll 8
    for (int j = 0; j < 64; ++j) {
        *reinterpret_cast<float4*>(hstart + (size_t)j * 8192 + c4 * 4) = h;
        float4 pp = *reinterpret_cast<const float4*>(P + (size_t)j * 8192 + c4 * 4);
        float4 vv = *reinterpret_cast<const float4*>(V + (size_t)j * 8192 + c4 * 4);
        h.x = pp.x * h.x + vv.x; h.y = pp.y * h.y + vv.y;
        h.z = pp.z * h.z + vv.z; h.w = pp.w * h.w + vv.w;
    }
}

template <bool BF16OUT, typename OUT>
__global__ void scan_final(const unsigned short* __restrict__ gh,
                           const float* __restrict__ hstart,
                           OUT* __restrict__ out) {
    const int h4 = threadIdx.x;
    const int j = blockIdx.y, b = blockIdx.z;
    const size_t base  = ((size_t)b * 4096 + (size_t)j * 64) * 2048 + h4 * 4;
    const size_t obase = ((size_t)b * 4096 + (size_t)j * 64) * 1024 + h4 * 4;
    float4 hq = *reinterpret_cast<const float4*>(hstart + (size_t)j * 8192 + b * 1024 + h4 * 4);
    float hv[4] = {hq.x, hq.y, hq.z, hq.w};
#pragma unroll 8
    for (int t = 0; t < 64; ++t) {
        ushort4 g  = *reinterpret_cast<const ushort4*>(gh + base + (size_t)t * 2048);
        ushort4 hd = *reinterpret_cast<const ushort4*>(gh + base + (size_t)t * 2048 + 1024);
        const unsigned short ga[4] = {g.x, g.y, g.z, g.w};
        const unsigned short ha[4] = {hd.x, hd.y, hd.z, hd.w};
#pragma unroll
        for (int c = 0; c < 4; ++c) {
            float gf = bf2f(ga[c]), hf = bf2f(ha[c]);
            float z  = sigmoidf_(gf);
            float cc = 1.0f - z;
            float gv = (hf >= 0.0f) ? (hf + 0.5f) : sigmoidf_(hf);
            hv[c] = cc * hv[c] + z * gv;
        }
        if (BF16OUT) {
            ushort4 o = make_ushort4(f2bf(hv[0]), f2bf(hv[1]), f2bf(hv[2]), f2bf(hv[3]));
            *reinterpret_cast<ushort4*>((unsigned short*)out + obase + (size_t)t * 1024) = o;
        } else {
            *reinterpret_cast<float4*>((float*)out + obase + (size_t)t * 1024) =
                make_float4(hv[0], hv[1], hv[2], hv[3]);
        }
    }
}

// ---------------------------------------------------------------------------
extern "C" void kernel_launch(void* const* d_in, const int* in_sizes, int n_in,
                              void* d_out, int out_size, void* d_ws, size_t ws_size,
                              hipStream_t stream) {
    const float* x  = (const float*)d_in[0];   // (8,4096,1024)
    const float* W0 = (const float*)d_in[1];   // (2048,1024)
    const float* b0 = (const float*)d_in[2];   // (2048,)
    const float* W1 = (const float*)d_in[3];   // (2048,1024)
    const float* b1 = (const float*)d_in[4];   // (2048,)
    float* out = (float*)d_out;                // (8,4096,1024) f32

    char* ws = (char*)d_ws;
    unsigned short* gh   = (unsigned short*)ws;                      // 128MB bf16
    unsigned short* abuf = (unsigned short*)(ws + 0x08000000);       // 64MB x/h1 bf16
    unsigned short* w0b  = (unsigned short*)(ws + 0x0C000000);       // 4MB
    unsigned short* w1b  = (unsigned short*)(ws + 0x0C400000);       // 4MB
    float*          P    = (float*)(ws + 0x0C800000);                // 2MB
    float*          V    = (float*)(ws + 0x0CA00000);                // 2MB
    float*          hst  = (float*)(ws + 0x0CC00000);                // 2MB

    const int M = 32768, N = 2048, K = 1024;

    f32_to_bf16_k<<<4194304 / 256, 256, 0, stream>>>(x,  abuf, 4194304);
    f32_to_bf16_k<<<262144 / 256, 256, 0, stream>>>(W0, w0b, 262144);
    f32_to_bf16_k<<<262144 / 256, 256, 0, stream>>>(W1, w1b, 262144);

    dim3 gg(M / 128, N / 128);   // (256,16)
    dim3 sg(1, 64, 8);           // (-, chunks, batch), 256 thr = 1024 ch / 4

    // layer 0
    gemm_bt<<<gg, 256, 0, stream>>>((const short*)abuf, (const short*)w0b, b0, gh, M, N, K);
    scan_partial<<<sg, 256, 0, stream>>>(gh, P, V);
    scan_combine<<<8, 256, 0, stream>>>(P, V, hst);
    scan_final<true, unsigned short><<<sg, 256, 0, stream>>>(gh, hst, abuf);  // h1 bf16

    // layer 1
    gemm_bt<<<gg, 256, 0, stream>>>((const short*)abuf, (const short*)w1b, b1, gh, M, N, K);
    scan_partial<<<sg, 256, 0, stream>>>(gh, P, V);
    scan_combine<<<8, 256, 0, stream>>>(P, V, hst);
    scan_final<false, float><<<sg, 256, 0, stream>>>(gh, hst, out);
}

// Round 4
// 906.112 us; speedup vs baseline: 1.3219x; 1.3219x over previous
//
#include <hip/hip_runtime.h>
#include <hip/hip_bf16.h>
#include <stdint.h>

// ============================================================================
// MinGRU (2 layers), B=8 S=4096 D=H=1024.
//   1. x (f32) -> bf16
//   2. GEMM0: gh = x_bf16 @ W0^T + b0  -> bf16 gh   (M=32768,N=2048,K=1024)
//   3. scan0: chunked linear scan -> h1 (bf16)
//   4. GEMM1: gh = h1 @ W1^T + b1 -> bf16 gh
//   5. scan1: -> out (f32)
// R4: GEMM back to A+B in LDS (R2 structure) + double-buffered LDS with a
//     single barrier per K-iter (loads for k+1 issued after the barrier ->
//     vmcnt drain waits on loads in flight for a full compute phase) + XCD
//     swizzle (16 n-blocks of one m-tile co-scheduled per XCD -> A from L2).
//     Scans: sigmoid via v_rcp_f32 (no fdiv), 128 chunks x 32 steps.
// ============================================================================

typedef __attribute__((ext_vector_type(8))) short bf16x8;   // 8 bf16 = 4 VGPRs
typedef __attribute__((ext_vector_type(4))) float f32x4;

__device__ __forceinline__ unsigned short f2bf(float f) {
    union { float f; unsigned int u; } x; x.f = f;
    unsigned int r = x.u + 0x7fffu + ((x.u >> 16) & 1u);   // RNE
    return (unsigned short)(r >> 16);
}
__device__ __forceinline__ float bf2f(unsigned short u) {
    union { unsigned int i; float f; } x; x.i = ((unsigned int)u) << 16;
    return x.f;
}
// sigmoid with HW rcp (~2.4e-7 rel err; output rounds to bf16 anyway)
__device__ __forceinline__ float fsig(float x) {
    return __builtin_amdgcn_rcpf(1.0f + __expf(-x));
}

// async 16B/lane global->LDS. lds base wave-uniform; HW dest = lds + lane*16.
__device__ __forceinline__ void async_cp16(const void* g, void* lds) {
    __builtin_amdgcn_global_load_lds(
        (const __attribute__((address_space(1))) unsigned int*)g,
        (__attribute__((address_space(3))) unsigned int*)lds, 16, 0, 0);
}

// ---------------------------------------------------------------------------
__global__ void f32_to_bf16_k(const float* __restrict__ in,
                              unsigned short* __restrict__ out, int n8) {
    int i = blockIdx.x * blockDim.x + threadIdx.x;
    if (i >= n8) return;
    const float4* p = reinterpret_cast<const float4*>(in);
    float4 a = p[2 * i], b = p[2 * i + 1];
    float f[8] = {a.x, a.y, a.z, a.w, b.x, b.y, b.z, b.w};
    union { unsigned short s[8]; uint4 v; } u;
#pragma unroll
    for (int j = 0; j < 8; ++j) u.s[j] = f2bf(f[j]);
    *reinterpret_cast<uint4*>(out + (size_t)i * 8) = u.v;
}

// ---------------------------------------------------------------------------
// GEMM: C[m,n] = sum_k A[m,k]*Wt[n,k] + bias[n], C bf16.
// 128x128 tile, BK=64, 4 waves (2x2), 16x16x32 MFMA, fragment-ordered LDS.
// Double-buffered (2x16KB A + 2x16KB B = 64KB), ONE barrier per K-iter.
// Grid is 1D (4096); (m,n) derived with an XCD swizzle: blocks on XCD x
// cover m-tiles [pass*128 + x*16, +16) for all n -> A window ~4MB = L2.
// ---------------------------------------------------------------------------
__global__ __launch_bounds__(256) void gemm_bt(
    const short* __restrict__ A, const short* __restrict__ Wt,
    const float* __restrict__ bias, unsigned short* __restrict__ C,
    int M, int N, int K)
{
    __shared__ __align__(16) short lds_a[16384];   // 2 bufs x 16KB
    __shared__ __align__(16) short lds_b[16384];

    const int tid  = threadIdx.x;
    const int lane = tid & 63;
    const int wave = tid >> 6;
    const int wm   = wave >> 1;            // 0..1
    const int wn   = wave & 1;             // 0..1

    // XCD swizzle: assume linear-id round-robin over 8 XCDs.
    const int bid  = blockIdx.x;           // 0..4095
    const int xcd  = bid & 7;
    const int slot = bid >> 3;             // 0..511
    const int pass = slot >> 8;            // 0..1
    const int r    = slot & 255;
    const int n_t  = r >> 4;               // 0..15
    const int mm   = r & 15;
    const int m0   = (pass * 128 + xcd * 16 + mm) * 128;
    const int n0   = n_t * 128;

    f32x4 acc[4][4] = {};

    // staging addresses: chunk c = wave*64 + lane + i*256
    const short* ga[4]; const short* gw[4]; int lofs[4];
#pragma unroll
    for (int i = 0; i < 4; ++i) {
        int c   = tid + i * 256;
        int blk = c >> 6;                       // tma=blk>>1, kc=blk&1
        int L   = c & 63;
        int row = (blk >> 1) * 16 + (L & 15);
        int col = (blk & 1) * 32 + ((L >> 4) * 8);
        ga[i] = A  + (size_t)(m0 + row) * K + col;
        gw[i] = Wt + (size_t)(n0 + row) * K + col;
        lofs[i] = (wave * 64 + i * 256) * 8;    // shorts; lane*16B implicit
    }

    // prologue: stage k=0 into buf 0
#pragma unroll
    for (int i = 0; i < 4; ++i) {
        async_cp16(ga[i], lds_a + lofs[i]);
        async_cp16(gw[i], lds_b + lofs[i]);
    }

    int idx = 0;
    for (int k0 = 64; k0 <= K; k0 += 64) {
        __syncthreads();   // drains vmcnt: buf[idx] ready (in flight 1 iter)
        if (k0 < K) {      // stage next tile into the other buffer
            int bo = (idx ^ 1) * 8192;
#pragma unroll
            for (int i = 0; i < 4; ++i) {
                async_cp16(ga[i] + k0, lds_a + bo + lofs[i]);
                async_cp16(gw[i] + k0, lds_b + bo + lofs[i]);
            }
        }
        const int bo = idx * 8192;
#pragma unroll
        for (int kc = 0; kc < 2; ++kc) {
            bf16x8 af[4], bf[4];
#pragma unroll
            for (int t = 0; t < 4; ++t) {
                int tma = wm * 4 + t;
                int tnb = wn * 4 + t;
                af[t] = *reinterpret_cast<const bf16x8*>(lds_a + bo + ((tma * 2 + kc) * 64 + lane) * 8);
                bf[t] = *reinterpret_cast<const bf16x8*>(lds_b + bo + ((tnb * 2 + kc) * 64 + lane) * 8);
            }
#pragma unroll
            for (int tm = 0; tm < 4; ++tm)
#pragma unroll
                for (int tn = 0; tn < 4; ++tn)
                    acc[tm][tn] = __builtin_amdgcn_mfma_f32_16x16x32_bf16(
                        af[tm], bf[kc == 0 ? tn : tn], acc[tm][tn], 0, 0, 0);
        }
        idx ^= 1;
    }

    // epilogue: C/D layout col=lane&15, row=quad*4+reg; store bf16
    const int quad = lane >> 4;
    const int lcol = lane & 15;
    float bv[4];
#pragma unroll
    for (int tn = 0; tn < 4; ++tn) bv[tn] = bias[n0 + wn * 64 + tn * 16 + lcol];
#pragma unroll
    for (int tm = 0; tm < 4; ++tm) {
        int mrow = m0 + wm * 64 + tm * 16 + quad * 4;
#pragma unroll
        for (int tn = 0; tn < 4; ++tn) {
            int ecol = n0 + wn * 64 + tn * 16 + lcol;
#pragma unroll
            for (int r2 = 0; r2 < 4; ++r2)
                C[(size_t)(mrow + r2) * N + ecol] = f2bf(acc[tm][tn][r2] + bv[tn]);
        }
    }
}

// ---------------------------------------------------------------------------
// Scans over bf16 gh:(B*S,2048); gate=[0,1024), hidden=[1024,2048).
// 128 chunks of 32 steps; 4 channels/thread. ch = b*1024+h.
// ---------------------------------------------------------------------------
__global__ void scan_partial(const unsigned short* __restrict__ gh,
                             float* __restrict__ P, float* __restrict__ V) {
    const int h4 = threadIdx.x;                 // 0..255 -> channels h4*4..+3
    const int j = blockIdx.y, b = blockIdx.z;
    const size_t base = ((size_t)b * 4096 + (size_t)j * 32) * 2048 + h4 * 4;
    float p[4] = {1, 1, 1, 1}, hl[4] = {0, 0, 0, 0};
#pragma unroll 8
    for (int t = 0; t < 32; ++t) {
        ushort4 g  = *reinterpret_cast<const ushort4*>(gh + base + (size_t)t * 2048);
        ushort4 hd = *reinterpret_cast<const ushort4*>(gh + base + (size_t)t * 2048 + 1024);
        const unsigned short ga[4] = {g.x, g.y, g.z, g.w};
        const unsigned short ha[4] = {hd.x, hd.y, hd.z, hd.w};
#pragma unroll
        for (int c = 0; c < 4; ++c) {
            float gf = bf2f(ga[c]), hf = bf2f(ha[c]);
            float z  = fsig(gf);
            float cc = 1.0f - z;
            float gv = (hf >= 0.0f) ? (hf + 0.5f) : fsig(hf);
            p[c]  = p[c] * cc;
            hl[c] = cc * hl[c] + z * gv;
        }
    }
    const int ch = b * 1024 + h4 * 4;
    *reinterpret_cast<float4*>(P + (size_t)j * 8192 + ch) = make_float4(p[0], p[1], p[2], p[3]);
    *reinterpret_cast<float4*>(V + (size_t)j * 8192 + ch) = make_float4(hl[0], hl[1], hl[2], hl[3]);
}

__global__ void scan_combine(const float* __restrict__ P,
                             const float* __restrict__ V,
                             float* __restrict__ hstart) {
    const int c4 = blockIdx.x * blockDim.x + threadIdx.x;  // 0..2047
    float4 h = make_float4(0.5f, 0.5f, 0.5f, 0.5f);        // h0 = g(0) = 0.5
#pragma unroll 8
    for (int j = 0; j < 128; ++j) {
        *reinterpret_cast<float4*>(hstart + (size_t)j * 8192 + c4 * 4) = h;
        float4 pp = *reinterpret_cast<const float4*>(P + (size_t)j * 8192 + c4 * 4);
        float4 vv = *reinterpret_cast<const float4*>(V + (size_t)j * 8192 + c4 * 4);
        h.x = pp.x * h.x + vv.x; h.y = pp.y * h.y + vv.y;
        h.z = pp.z * h.z + vv.z; h.w = pp.w * h.w + vv.w;
    }
}

template <bool BF16OUT, typename OUT>
__global__ void scan_final(const unsigned short* __restrict__ gh,
                           const float* __restrict__ hstart,
                           OUT* __restrict__ out) {
    const int h4 = threadIdx.x;
    const int j = blockIdx.y, b = blockIdx.z;
    const size_t base  = ((size_t)b * 4096 + (size_t)j * 32) * 2048 + h4 * 4;
    const size_t obase = ((size_t)b * 4096 + (size_t)j * 32) * 1024 + h4 * 4;
    float4 hq = *reinterpret_cast<const float4*>(hstart + (size_t)j * 8192 + b * 1024 + h4 * 4);
    float hv[4] = {hq.x, hq.y, hq.z, hq.w};
#pragma unroll 8
    for (int t = 0; t < 32; ++t) {
        ushort4 g  = *reinterpret_cast<const ushort4*>(gh + base + (size_t)t * 2048);
        ushort4 hd = *reinterpret_cast<const ushort4*>(gh + base + (size_t)t * 2048 + 1024);
        const unsigned short ga[4] = {g.x, g.y, g.z, g.w};
        const unsigned short ha[4] = {hd.x, hd.y, hd.z, hd.w};
#pragma unroll
        for (int c = 0; c < 4; ++c) {
            float gf = bf2f(ga[c]), hf = bf2f(ha[c]);
            float z  = fsig(gf);
            float cc = 1.0f - z;
            float gv = (hf >= 0.0f) ? (hf + 0.5f) : fsig(hf);
            hv[c] = cc * hv[c] + z * gv;
        }
        if (BF16OUT) {
            ushort4 o = make_ushort4(f2bf(hv[0]), f2bf(hv[1]), f2bf(hv[2]), f2bf(hv[3]));
            *reinterpret_cast<ushort4*>((unsigned short*)out + obase + (size_t)t * 1024) = o;
        } else {
            *reinterpret_cast<float4*>((float*)out + obase + (size_t)t * 1024) =
                make_float4(hv[0], hv[1], hv[2], hv[3]);
        }
    }
}

// ---------------------------------------------------------------------------
extern "C" void kernel_launch(void* const* d_in, const int* in_sizes, int n_in,
                              void* d_out, int out_size, void* d_ws, size_t ws_size,
                              hipStream_t stream) {
    const float* x  = (const float*)d_in[0];   // (8,4096,1024)
    const float* W0 = (const float*)d_in[1];   // (2048,1024)
    const float* b0 = (const float*)d_in[2];   // (2048,)
    const float* W1 = (const float*)d_in[3];   // (2048,1024)
    const float* b1 = (const float*)d_in[4];   // (2048,)
    float* out = (float*)d_out;                // (8,4096,1024) f32

    char* ws = (char*)d_ws;
    unsigned short* gh   = (unsigned short*)ws;                      // 128MB bf16
    unsigned short* abuf = (unsigned short*)(ws + 0x08000000);       // 64MB x/h1 bf16
    unsigned short* w0b  = (unsigned short*)(ws + 0x0C000000);       // 4MB
    unsigned short* w1b  = (unsigned short*)(ws + 0x0C400000);       // 4MB
    float*          P    = (float*)(ws + 0x0C800000);                // 4MB
    float*          V    = (float*)(ws + 0x0CC00000);                // 4MB
    float*          hst  = (float*)(ws + 0x0D000000);                // 4MB

    const int M = 32768, N = 2048, K = 1024;

    f32_to_bf16_k<<<4194304 / 256, 256, 0, stream>>>(x,  abuf, 4194304);
    f32_to_bf16_k<<<262144 / 256, 256, 0, stream>>>(W0, w0b, 262144);
    f32_to_bf16_k<<<262144 / 256, 256, 0, stream>>>(W1, w1b, 262144);

    dim3 sg(1, 128, 8);          // (-, chunks, batch), 256 thr = 1024 ch / 4

    // layer 0
    gemm_bt<<<4096, 256, 0, stream>>>((const short*)abuf, (const short*)w0b, b0, gh, M, N, K);
    scan_partial<<<sg, 256, 0, stream>>>(gh, P, V);
    scan_combine<<<8, 256, 0, stream>>>(P, V, hst);
    scan_final<true, unsigned short><<<sg, 256, 0, stream>>>(gh, hst, abuf);  // h1 bf16

    // layer 1
    gemm_bt<<<4096, 256, 0, stream>>>((const short*)abuf, (const short*)w1b, b1, gh, M, N, K);
    scan_partial<<<sg, 256, 0, stream>>>(gh, P, V);
    scan_combine<<<8, 256, 0, stream>>>(P, V, hst);
    scan_final<false, float><<<sg, 256, 0, stream>>>(gh, hst, out);
}